// Round 1
// baseline (452.976 us; speedup 1.0000x reference)
//
#include <hip/hip_runtime.h>

#define SEQ_LEN 512
#define BATCH   512
#define NT      64

// ---------------------------------------------------------------------------
// Normalizer (forward algorithm). One wave (64 lanes) per batch element.
// lane j owns tag j. E[i] = exp(trans[i][j]) held in 64 VGPRs (column j).
// Per step: p[j] = sum_i q[i]*E[i][j] with q[i]=exp(score[i]-S) broadcast
// through double-buffered LDS; next = em + S + log(p). S = readfirstlane.
// ---------------------------------------------------------------------------
__global__ __launch_bounds__(64) void crf_denom_kernel(
    const float* __restrict__ emissions,  // [T, B, NT]
    const int*   __restrict__ mask,       // [T, B]
    const float* __restrict__ startT,     // [NT]
    const float* __restrict__ endT,       // [NT]
    const float* __restrict__ trans,      // [NT, NT]
    float* __restrict__ out)
{
    const int b = blockIdx.x;
    const int j = threadIdx.x;

    // exp(transitions) column j -> registers (coalesced loads: fixed i, lanes j)
    float E[NT];
#pragma unroll
    for (int i = 0; i < NT; ++i)
        E[i] = __expf(trans[i * NT + j]);

    __shared__ float qs[2][NT];

    float score = startT[j] + emissions[(size_t)b * NT + j];
    float S = __uint_as_float(__builtin_amdgcn_readfirstlane(__float_as_uint(score)));
    qs[0][j] = __expf(score - S);
    __syncthreads();

    float e_cur = emissions[(size_t)(1 * BATCH + b) * NT + j];

    for (int t = 1; t < SEQ_LEN; ++t) {
        // prefetch next step's emission row early (hides HBM/L2 latency)
        float e_next = (t + 1 < SEQ_LEN)
            ? emissions[(size_t)((t + 1) * BATCH + b) * NT + j] : 0.f;
        const int m = mask[t * BATCH + b];

        const float4* q4 = (const float4*)qs[(t - 1) & 1];
        float a0 = 0.f, a1 = 0.f, a2 = 0.f, a3 = 0.f;
#pragma unroll
        for (int k = 0; k < NT / 4; ++k) {
            const float4 qv = q4[k];   // broadcast read, conflict-free
            a0 = fmaf(qv.x, E[4 * k + 0], a0);
            a1 = fmaf(qv.y, E[4 * k + 1], a1);
            a2 = fmaf(qv.z, E[4 * k + 2], a2);
            a3 = fmaf(qv.w, E[4 * k + 3], a3);
        }
        const float p = (a0 + a1) + (a2 + a3);
        const float cand = e_cur + S + __logf(p);
        score = m ? cand : score;
        S = __uint_as_float(__builtin_amdgcn_readfirstlane(__float_as_uint(score)));
        qs[t & 1][j] = __expf(score - S);   // write other buffer: no WAR hazard
        __syncthreads();                    // single wave: ~just a waitcnt
        e_cur = e_next;
    }

    // denominator_b = logsumexp_j(score[j] + endT[j])
    const float v = score + endT[j];
    float mx = v;
#pragma unroll
    for (int off = 32; off > 0; off >>= 1)
        mx = fmaxf(mx, __shfl_xor(mx, off));
    float s = __expf(v - mx);
#pragma unroll
    for (int off = 32; off > 0; off >>= 1)
        s += __shfl_xor(s, off);
    if (j == 0) {
        const float den = mx + __logf(s);
        atomicAdd(out, -den);   // llh = numerator - denominator
    }
}

// ---------------------------------------------------------------------------
// Numerator: pure gather-sum, independent over (t,b). One wave per b,
// lane handles t = lane, lane+64, ... (8 iterations).
// ---------------------------------------------------------------------------
__global__ __launch_bounds__(64) void crf_num_kernel(
    const float* __restrict__ emissions,  // [T, B, NT]
    const int*   __restrict__ tags,       // [T, B]
    const int*   __restrict__ mask,       // [T, B]
    const float* __restrict__ startT,
    const float* __restrict__ endT,
    const float* __restrict__ trans,
    float* __restrict__ out)
{
    const int b    = blockIdx.x;
    const int lane = threadIdx.x;

    float acc = 0.f;
    int   cnt = 0;
#pragma unroll
    for (int t0 = 0; t0 < SEQ_LEN; t0 += 64) {
        const int t = t0 + lane;
        const int m = mask[t * BATCH + b];
        cnt += m ? 1 : 0;
        if (t >= 1 && m) {
            const int tg = tags[t * BATCH + b];
            const int tp = tags[(t - 1) * BATCH + b];
            acc += trans[tp * NT + tg]
                 + emissions[(size_t)(t * BATCH + b) * NT + tg];
        }
    }
    // wave reduce (sum) acc and cnt
#pragma unroll
    for (int off = 32; off > 0; off >>= 1) {
        acc += __shfl_xor(acc, off);
        cnt += __shfl_xor(cnt, off);
    }
    if (lane == 0) {
        const int tag0 = tags[b];  // t = 0
        float num = startT[tag0] + emissions[(size_t)b * NT + tag0] + acc;
        const int seq_end = cnt - 1;              // mask count - 1
        const int last    = tags[seq_end * BATCH + b];
        num += endT[last];
        atomicAdd(out, num);
    }
}

extern "C" void kernel_launch(void* const* d_in, const int* in_sizes, int n_in,
                              void* d_out, int out_size, void* d_ws, size_t ws_size,
                              hipStream_t stream) {
    const float* emissions = (const float*)d_in[0];
    const int*   tags      = (const int*)  d_in[1];
    const int*   mask      = (const int*)  d_in[2];
    const float* startT    = (const float*)d_in[3];
    const float* endT      = (const float*)d_in[4];
    const float* trans     = (const float*)d_in[5];
    float* out = (float*)d_out;

    // harness poisons d_out with 0xAA before every launch -> zero it here
    hipMemsetAsync(out, 0, sizeof(float), stream);

    crf_num_kernel<<<BATCH, 64, 0, stream>>>(
        emissions, tags, mask, startT, endT, trans, out);
    crf_denom_kernel<<<BATCH, 64, 0, stream>>>(
        emissions, mask, startT, endT, trans, out);
}

// Round 2
// 334.027 us; speedup vs baseline: 1.3561x; 1.3561x over previous
//
#include <hip/hip_runtime.h>

#define T  512
#define B  512
#define NT 64

typedef float v2f __attribute__((ext_vector_type(2)));

// ---------------------------------------------------------------------------
// Normalizer (forward algorithm). One wave per batch element, lane j = tag j.
// Product form: score_j(t) = S + log q_j.  Per step:
//   p_j = sum_i q_i * E[i][j]            (E = exp(trans), column j in VGPRs)
//   q'_j = (p_j * rcp(P)) * X_t          P = readfirstlane(p), X_t = exp(e_t - ef_t)
//   S   += log(P) + ef_t                 (off critical path)
// X/ef/mask/emissions ride a 4-deep register pipeline (HBM latency hiding).
// Single-wave block: no __syncthreads; DS ops are in-order per wave, so
// single-buffer LDS broadcast of q is safe (reads precede the write in
// program order each step).
// ---------------------------------------------------------------------------
__global__ __launch_bounds__(64) void crf_denom_kernel(
    const float* __restrict__ emissions,  // [T, B, NT]
    const int*   __restrict__ mask,       // [T, B]
    const float* __restrict__ startT,     // [NT]
    const float* __restrict__ endT,       // [NT]
    const float* __restrict__ trans,      // [NT, NT]
    float* __restrict__ out)
{
    const int b = blockIdx.x;
    const int j = threadIdx.x;

    // E column j as float2 pairs over i (enables v_pk_fma_f32)
    v2f Ep[NT / 2];
#pragma unroll
    for (int m = 0; m < NT / 2; ++m) {
        Ep[m].x = __expf(trans[(2 * m)     * NT + j]);
        Ep[m].y = __expf(trans[(2 * m + 1) * NT + j]);
    }

    __shared__ __align__(16) float qs[NT];

    const float* pe = emissions + (size_t)b * NT + j;  // step stride B*NT
    const int*   pm = mask + b;                        // step stride B

    // t = 0 init: q_0lane = 1 by construction
    const float score0 = startT[j] + pe[0];
    float S = __uint_as_float(__builtin_amdgcn_readfirstlane(__float_as_uint(score0)));
    float q = __expf(score0 - S);
    qs[j] = q;

    // prologue: pipeline holds e(t+1..t+4) at start of step t (t=1)
    float e1 = pe[(size_t)1 * B * NT];
    float e2 = pe[(size_t)2 * B * NT];
    float e3 = pe[(size_t)3 * B * NT];
    float e4 = pe[(size_t)4 * B * NT];
    float e5 = pe[(size_t)5 * B * NT];
    int m1 = pm[1 * B], m2 = pm[2 * B], m3 = pm[3 * B], m4 = pm[4 * B], m5 = pm[5 * B];

    float ef = __uint_as_float(__builtin_amdgcn_readfirstlane(__float_as_uint(e1)));
    float X  = __expf(e1 - ef);   // X for t=1
    int   mc = m1;                // mask for t=1
    e1 = e2; e2 = e3; e3 = e4; e4 = e5;
    m1 = m2; m2 = m3; m3 = m4; m4 = m5;

#pragma unroll 4
    for (int t = 1; t < T; ++t) {
        // append t+5 (arrives by step t+4 — ~4 steps of latency hiding)
        const int tn = (t + 5 < T) ? (t + 5) : (T - 1);
        const float eN = pe[(size_t)tn * B * NT];
        const int   mN = pm[(size_t)tn * B];

        // matvec: p_j = sum_i q_i * E[i][j]  (broadcast float4 LDS reads)
        const float4* q4 = (const float4*)qs;
        v2f a0 = {0.f, 0.f}, a1 = {0.f, 0.f}, a2 = {0.f, 0.f}, a3 = {0.f, 0.f};
#pragma unroll
        for (int k = 0; k < NT / 4; k += 2) {
            const float4 u = q4[k];
            const float4 w = q4[k + 1];
            a0 = __builtin_elementwise_fma((v2f){u.x, u.y}, Ep[2 * k],     a0);
            a1 = __builtin_elementwise_fma((v2f){u.z, u.w}, Ep[2 * k + 1], a1);
            a2 = __builtin_elementwise_fma((v2f){w.x, w.y}, Ep[2 * k + 2], a2);
            a3 = __builtin_elementwise_fma((v2f){w.z, w.w}, Ep[2 * k + 3], a3);
        }
        const v2f s01 = a0 + a1;
        const v2f s23 = a2 + a3;
        const v2f ss  = s01 + s23;
        const float p = ss.x + ss.y;

        // next step's X (independent of matvec — schedules into the bubbles)
        const float efn = __uint_as_float(__builtin_amdgcn_readfirstlane(__float_as_uint(e1)));
        const float Xn  = __expf(e1 - efn);

        // tail: renormalize via rcp (no transcendental on critical path)
        const float P  = __uint_as_float(__builtin_amdgcn_readfirstlane(__float_as_uint(p)));
        const float qn = p * __builtin_amdgcn_rcpf(P) * X;
        q = mc ? qn : q;
        qs[j] = q;
        S = mc ? (S + __logf(P) + ef) : S;   // scalar side, lags freely

        // shift pipelines
        X = Xn; ef = efn; mc = m1;
        e1 = e2; e2 = e3; e3 = e4; e4 = eN;
        m1 = m2; m2 = m3; m3 = m4; m4 = mN;
    }

    // denominator_b = S + log( sum_j q_j * exp(endT_j) )
    float v = q * __expf(endT[j]);
#pragma unroll
    for (int off = 32; off > 0; off >>= 1)
        v += __shfl_xor(v, off);
    if (j == 0)
        atomicAdd(out, -(S + __logf(v)));   // llh = num - den
}

// ---------------------------------------------------------------------------
// Numerator main part: flat grid-stride over (t,b), b fast-varying so
// tags/mask loads are fully coalesced. Also accumulates per-b mask counts
// into d_ws for the end-transition kernel.
// ---------------------------------------------------------------------------
__global__ __launch_bounds__(256) void crf_num_kernel(
    const float* __restrict__ emissions,
    const int*   __restrict__ tags,
    const int*   __restrict__ mask,
    const float* __restrict__ startT,
    const float* __restrict__ trans,
    float* __restrict__ out,
    int*   __restrict__ cnt_ws)
{
    const int tid = blockIdx.x * 256 + threadIdx.x;   // 32768 threads
    float acc = 0.f;
    int   cnt = 0;
    const int bb = tid & (B - 1);   // stride 32768 ≡ 0 mod B → b constant per thread
#pragma unroll
    for (int k = 0; k < (T * B) / 32768; ++k) {       // 8 iters
        const int idx = tid + k * 32768;
        const int t   = idx >> 9;
        const int m   = mask[idx];
        cnt += m;
        const int tg = tags[idx];
        if (t == 0) {
            acc += startT[tg] + emissions[(size_t)idx * NT + tg];
        } else if (m) {
            const int tp = tags[idx - B];
            acc += trans[tp * NT + tg] + emissions[(size_t)idx * NT + tg];
        }
    }
    atomicAdd(&cnt_ws[bb], cnt);
#pragma unroll
    for (int off = 32; off > 0; off >>= 1)
        acc += __shfl_xor(acc, off);
    if ((threadIdx.x & 63) == 0)
        atomicAdd(out, acc);
}

// ---------------------------------------------------------------------------
// End transitions: needs complete per-b mask counts (runs after crf_num).
// ---------------------------------------------------------------------------
__global__ __launch_bounds__(256) void crf_end_kernel(
    const int*   __restrict__ tags,
    const float* __restrict__ endT,
    const int*   __restrict__ cnt_ws,
    float* __restrict__ out)
{
    const int b = blockIdx.x * 256 + threadIdx.x;     // grid 2 x 256
    const int cnt  = cnt_ws[b];
    const int last = tags[(size_t)(cnt - 1) * B + b];
    float v = endT[last];
#pragma unroll
    for (int off = 32; off > 0; off >>= 1)
        v += __shfl_xor(v, off);
    if ((threadIdx.x & 63) == 0)
        atomicAdd(out, v);
}

extern "C" void kernel_launch(void* const* d_in, const int* in_sizes, int n_in,
                              void* d_out, int out_size, void* d_ws, size_t ws_size,
                              hipStream_t stream) {
    const float* emissions = (const float*)d_in[0];
    const int*   tags      = (const int*)  d_in[1];
    const int*   mask      = (const int*)  d_in[2];
    const float* startT    = (const float*)d_in[3];
    const float* endT      = (const float*)d_in[4];
    const float* trans     = (const float*)d_in[5];
    float* out   = (float*)d_out;
    int*   cntws = (int*)d_ws;

    hipMemsetAsync(out, 0, sizeof(float), stream);
    hipMemsetAsync(cntws, 0, B * sizeof(int), stream);

    crf_num_kernel<<<128, 256, 0, stream>>>(
        emissions, tags, mask, startT, trans, out, cntws);
    crf_end_kernel<<<2, 256, 0, stream>>>(tags, endT, cntws, out);
    crf_denom_kernel<<<B, 64, 0, stream>>>(
        emissions, mask, startT, endT, trans, out);
}